// Round 3
// baseline (40105.621 us; speedup 1.0000x reference)
//
#include <hip/hip_runtime.h>
#include <math.h>

#define IN_DIM 1024
#define H2     2048
#define HID    1024
#define NEXP   64
#define TOPK   8
#define RISK_TH 1.5e-4f

// ---------------- big SGEMM: C = relu(A@B + bias), fp32 ----------------
#define BM 128
#define BN 128
#define BK 16
#define LDAS 132

__global__ __launch_bounds__(256, 4)
void sgemm_relu_kernel(const float* __restrict__ A, const float* __restrict__ B,
                       const float* __restrict__ bias, float* __restrict__ C,
                       int N, int K)
{
    __shared__ __align__(16) float As[BK][LDAS]; // As[k][m]
    __shared__ __align__(16) float Bs[BK][BN];   // Bs[k][n]

    const int tid = threadIdx.x;
    const int tx  = tid & 15;
    const int ty  = tid >> 4;
    const long bm = (long)blockIdx.y * BM;
    const long bn = (long)blockIdx.x * BN;

    const float* Ab = A + bm * K;
    const float* Bb = B + bn;

    float acc[8][8];
#pragma unroll
    for (int i = 0; i < 8; ++i)
#pragma unroll
        for (int j = 0; j < 8; ++j) acc[i][j] = 0.f;

    float4 aR[2], bR[2];
#pragma unroll
    for (int j = 0; j < 2; ++j) {
        int idx = tid + (j << 8);
        int ar = idx >> 2, ac = (idx & 3) << 2;
        aR[j] = *(const float4*)(Ab + (long)ar * K + ac);
        int br = idx >> 5, bc = (idx & 31) << 2;
        bR[j] = *(const float4*)(Bb + (long)br * N + bc);
    }

    int kt = 0;
    for (;;) {
#pragma unroll
        for (int j = 0; j < 2; ++j) {
            int idx = tid + (j << 8);
            int ar = idx >> 2, ac = (idx & 3) << 2;
            As[ac + 0][ar] = aR[j].x;
            As[ac + 1][ar] = aR[j].y;
            As[ac + 2][ar] = aR[j].z;
            As[ac + 3][ar] = aR[j].w;
            int br = idx >> 5, bc = (idx & 31) << 2;
            *(float4*)&Bs[br][bc] = bR[j];
        }
        __syncthreads();

        kt += BK;
        if (kt < K) {
#pragma unroll
            for (int j = 0; j < 2; ++j) {
                int idx = tid + (j << 8);
                int ar = idx >> 2, ac = (idx & 3) << 2;
                aR[j] = *(const float4*)(Ab + (long)ar * K + kt + ac);
                int br = idx >> 5, bc = (idx & 31) << 2;
                bR[j] = *(const float4*)(Bb + (long)(kt + br) * N + bc);
            }
        }

#pragma unroll
        for (int k = 0; k < BK; ++k) {
            float a[8], b[8];
            *(float4*)&a[0] = *(const float4*)&As[k][ty * 8];
            *(float4*)&a[4] = *(const float4*)&As[k][ty * 8 + 4];
            *(float4*)&b[0] = *(const float4*)&Bs[k][tx * 8];
            *(float4*)&b[4] = *(const float4*)&Bs[k][tx * 8 + 4];
#pragma unroll
            for (int i = 0; i < 8; ++i)
#pragma unroll
                for (int j = 0; j < 8; ++j)
                    acc[i][j] = fmaf(a[i], b[j], acc[i][j]);
        }
        __syncthreads();
        if (kt >= K) break;
    }

    float bv[8];
#pragma unroll
    for (int j = 0; j < 8; ++j) bv[j] = bias[bn + tx * 8 + j];
#pragma unroll
    for (int i = 0; i < 8; ++i) {
        long row = bm + ty * 8 + i;
        float o[8];
#pragma unroll
        for (int j = 0; j < 8; ++j) {
            float v = acc[i][j] + bv[j];
            o[j] = fmaxf(v, 0.f);
        }
        float* Cp = C + row * N + bn + tx * 8;
        *(float4*)(Cp)     = *(const float4*)&o[0];
        *(float4*)(Cp + 4) = *(const float4*)&o[4];
    }
}

// ---------------- small GEMM (N=64): C = A@B + bias, fp32 ----------------
#define SBM 64
#define SBK 32
#define SLDA 68

__global__ __launch_bounds__(256, 4)
void small_gemm_kernel(const float* __restrict__ A, const float* __restrict__ B,
                       const float* __restrict__ bias, float* __restrict__ C,
                       int K)
{
    __shared__ __align__(16) float Hs[SBK][SLDA];
    __shared__ __align__(16) float Ws[SBK][NEXP];
    const int tid = threadIdx.x;
    const int tx = tid & 15;
    const int ty = tid >> 4;
    const long bm = (long)blockIdx.x * SBM;
    const float* Ab = A + bm * K;

    float acc[4][4];
#pragma unroll
    for (int i = 0; i < 4; ++i)
#pragma unroll
        for (int j = 0; j < 4; ++j) acc[i][j] = 0.f;

    float4 aR[2], bR[2];
#pragma unroll
    for (int j = 0; j < 2; ++j) {
        int idx = tid + (j << 8);
        int ar = idx >> 3, ac = (idx & 7) << 2;
        aR[j] = *(const float4*)(Ab + (long)ar * K + ac);
        int br = idx >> 4, bc = (idx & 15) << 2;
        bR[j] = *(const float4*)(B + (long)br * NEXP + bc);
    }

    int kt = 0;
    for (;;) {
#pragma unroll
        for (int j = 0; j < 2; ++j) {
            int idx = tid + (j << 8);
            int ar = idx >> 3, ac = (idx & 7) << 2;
            Hs[ac + 0][ar] = aR[j].x;
            Hs[ac + 1][ar] = aR[j].y;
            Hs[ac + 2][ar] = aR[j].z;
            Hs[ac + 3][ar] = aR[j].w;
            int br = idx >> 4, bc = (idx & 15) << 2;
            *(float4*)&Ws[br][bc] = bR[j];
        }
        __syncthreads();

        kt += SBK;
        if (kt < K) {
#pragma unroll
            for (int j = 0; j < 2; ++j) {
                int idx = tid + (j << 8);
                int ar = idx >> 3, ac = (idx & 7) << 2;
                aR[j] = *(const float4*)(Ab + (long)ar * K + kt + ac);
                int br = idx >> 4, bc = (idx & 15) << 2;
                bR[j] = *(const float4*)(B + (long)(kt + br) * NEXP + bc);
            }
        }

#pragma unroll
        for (int k = 0; k < SBK; ++k) {
            float a[4], b[4];
            *(float4*)&a[0] = *(const float4*)&Hs[k][ty * 4];
            *(float4*)&b[0] = *(const float4*)&Ws[k][tx * 4];
#pragma unroll
            for (int i = 0; i < 4; ++i)
#pragma unroll
                for (int j = 0; j < 4; ++j)
                    acc[i][j] = fmaf(a[i], b[j], acc[i][j]);
        }
        __syncthreads();
        if (kt >= K) break;
    }

    float bv[4];
#pragma unroll
    for (int j = 0; j < 4; ++j) bv[j] = bias[tx * 4 + j];
#pragma unroll
    for (int i = 0; i < 4; ++i) {
        long row = bm + ty * 4 + i;
        float o[4];
#pragma unroll
        for (int j = 0; j < 4; ++j) o[j] = acc[i][j] + bv[j];
        *(float4*)(C + row * NEXP + tx * 4) = *(const float4*)&o[0];
    }
}

// ---------------- router (fp32) + risky-row detection ----------------
__global__ __launch_bounds__(256)
void router_kernel(const float* __restrict__ logits, const float* __restrict__ nlog,
                   const float* __restrict__ noise, float* __restrict__ rout,
                   float* __restrict__ idx_out, int rows, int rowBase,
                   int* __restrict__ ctrl, int* __restrict__ list, int maxr)
{
    const int wave = threadIdx.x >> 6;
    const int lane = threadIdx.x & 63;
    const long row = (long)blockIdx.x * 4 + wave;
    if (row >= rows) return;

    float lg = logits[row * NEXP + lane];
    float nl = nlog[row * NEXP + lane];
    float nz = noise[row * NEXP + lane];
    float sp = fmaxf(nl, 0.f) + log1pf(expf(-fabsf(nl)));
    float v  = lg + nz * sp;

    float orig = v;
    float work = v;
    bool  sel  = false;
    float myidx = 0.f;
    float m = 0.f, ssum = 0.f;
    float prev = 0.f, minGap = INFINITY;

#pragma unroll
    for (int r = 0; r < TOPK + 1; ++r) {   // 9 rounds: top-8 + gap to rank-9
        float bvv = work;
        int   bi  = lane;
#pragma unroll
        for (int off = 32; off > 0; off >>= 1) {
            float ov = __shfl_xor(bvv, off);
            int   oi = __shfl_xor(bi, off);
            if (ov > bvv || (ov == bvv && oi < bi)) { bvv = ov; bi = oi; }
        }
        if (r > 0) minGap = fminf(minGap, prev - bvv);
        prev = bvv;
        if (r < TOPK) {
            if (r == 0) m = bvv;
            ssum += expf(bvv - m);
            if (lane == bi) { work = -INFINITY; sel = true; }
            if (lane == r)  myidx = (float)bi;
        }
    }

    float p = sel ? expf(orig - m) / ssum : 0.f;
    rout[row * NEXP + lane] = p;
    if (lane < TOPK) idx_out[row * TOPK + lane] = myidx;

    if (lane == 0 && minGap < RISK_TH) {
        int slot = atomicAdd(ctrl, 1);
        if (slot < maxr) list[slot] = rowBase + (int)row;
    }
}

// ---------------- phase C: fp64 recompute of risky rows ----------------
__global__ void init_kernel(int* ctrl) { if (threadIdx.x == 0) ctrl[0] = 0; }

__global__ void pad_kernel(int* ctrl, int* list, int maxr)
{
    int cnt = ctrl[0]; if (cnt > maxr) cnt = maxr;
    int rounded = (cnt + 63) & ~63; if (rounded > maxr) rounded = maxr;
    if (threadIdx.x == 0) { ctrl[1] = rounded; ctrl[2] = cnt; }
    int fill = (cnt > 0) ? list[0] : 0;
    for (int i = cnt + threadIdx.x; i < rounded; i += blockDim.x) list[i] = fill;
}

#define DBM 64
#define DBN 64
#define DBK 16

__global__ __launch_bounds__(256)
void dgemm_f64(const double* __restrict__ A64, const float* __restrict__ A32,
               const int* __restrict__ rowList,
               const float* __restrict__ B, const float* __restrict__ bias,
               double* __restrict__ C, int N, int K, int doRelu,
               const int* __restrict__ ctrl)
{
    const int mBase = blockIdx.y * DBM;
    if (mBase >= ctrl[1]) return;

    __shared__ double As[DBK][DBM + 1];
    __shared__ double Bs[DBK][DBN];
    __shared__ int rowIdx[DBM];

    const int tid = threadIdx.x;
    const int tx = tid & 15;
    const int ty = tid >> 4;
    const int nBase = blockIdx.x * DBN;

    if (A32 && tid < DBM) rowIdx[tid] = rowList[mBase + tid];
    __syncthreads();

    double acc[4][4];
#pragma unroll
    for (int i = 0; i < 4; ++i)
#pragma unroll
        for (int j = 0; j < 4; ++j) acc[i][j] = 0.0;

    for (int kt = 0; kt < K; kt += DBK) {
#pragma unroll
        for (int j = 0; j < 4; ++j) {
            int idx = tid + (j << 8);
            int ar = idx >> 4, ak = idx & 15;
            double av;
            if (A32) av = (double)A32[(long)rowIdx[ar] * K + kt + ak];
            else     av = A64[(long)(mBase + ar) * K + kt + ak];
            As[ak][ar] = av;
            int br = idx >> 6, bc = idx & 63;
            // FIX: B tile must come from this block's column strip (nBase)
            Bs[br][bc] = (double)B[(long)(kt + br) * N + nBase + bc];
        }
        __syncthreads();

#pragma unroll
        for (int k = 0; k < DBK; ++k) {
            double a[4], b[4];
#pragma unroll
            for (int i = 0; i < 4; ++i) a[i] = As[k][ty * 4 + i];
#pragma unroll
            for (int j = 0; j < 4; ++j) b[j] = Bs[k][tx * 4 + j];
#pragma unroll
            for (int i = 0; i < 4; ++i)
#pragma unroll
                for (int j = 0; j < 4; ++j)
                    acc[i][j] = fma(a[i], b[j], acc[i][j]);
        }
        __syncthreads();
    }

#pragma unroll
    for (int i = 0; i < 4; ++i) {
        long row = mBase + ty * 4 + i;
#pragma unroll
        for (int j = 0; j < 4; ++j) {
            int n = nBase + tx * 4 + j;
            double v = acc[i][j] + (double)bias[n];
            if (doRelu) v = fmax(v, 0.0);
            C[row * N + n] = v;
        }
    }
}

__global__ __launch_bounds__(256)
void router_fix_kernel(const double* __restrict__ lgd, const double* __restrict__ nld,
                       const float* __restrict__ noise, float* __restrict__ rout,
                       float* __restrict__ idx_out,
                       const int* __restrict__ ctrl, const int* __restrict__ list)
{
    const int wave = threadIdx.x >> 6;
    const int lane = threadIdx.x & 63;
    const int i = blockIdx.x * 4 + wave;
    if (i >= ctrl[2]) return;
    const long row = list[i];

    double lg = lgd[(long)i * NEXP + lane];
    double nl = nld[(long)i * NEXP + lane];
    double nz = (double)noise[row * NEXP + lane];
    double sp = fmax(nl, 0.0) + log1p(exp(-fabs(nl)));
    double v  = lg + nz * sp;

    double orig = v, work = v;
    bool sel = false;
    float myidx = 0.f;
    double m = 0.0, ssum = 0.0;

#pragma unroll
    for (int r = 0; r < TOPK; ++r) {
        double bvv = work;
        int    bi  = lane;
#pragma unroll
        for (int off = 32; off > 0; off >>= 1) {
            double ov = __shfl_xor(bvv, off);
            int    oi = __shfl_xor(bi, off);
            if (ov > bvv || (ov == bvv && oi < bi)) { bvv = ov; bi = oi; }
        }
        if (r == 0) m = bvv;
        ssum += exp(bvv - m);
        if (lane == bi) { work = -INFINITY; sel = true; }
        if (lane == r)  myidx = (float)bi;
    }

    double p = sel ? exp(orig - m) / ssum : 0.0;
    rout[row * NEXP + lane] = (float)p;
    if (lane < TOPK) idx_out[row * TOPK + lane] = myidx;
}

// ---------------- launch ----------------
extern "C" void kernel_launch(void* const* d_in, const int* in_sizes, int n_in,
                              void* d_out, int out_size, void* d_ws, size_t ws_size,
                              hipStream_t stream)
{
    const float* x     = (const float*)d_in[0];
    const float* noise = (const float*)d_in[1];
    const float* w1 = (const float*)d_in[2];
    const float* b1 = (const float*)d_in[3];
    const float* w2 = (const float*)d_in[4];
    const float* b2 = (const float*)d_in[5];
    const float* wn = (const float*)d_in[6];
    const float* bn = (const float*)d_in[7];
    const float* w3 = (const float*)d_in[8];
    const float* b3 = (const float*)d_in[9];
    const float* w4 = (const float*)d_in[10];
    const float* b4 = (const float*)d_in[11];
    const float* wz = (const float*)d_in[12];
    const float* bz = (const float*)d_in[13];
    float* out = (float*)d_out;

    const int Ntok = in_sizes[0] / IN_DIM;   // 32768

    int chunk = 8192;
    while (chunk > 128) {
        size_t needb = (size_t)chunk * (2 * H2 + 2 * NEXP) * sizeof(float) + 32768;
        if (needb <= ws_size) break;
        chunk >>= 1;
    }
    if (chunk > Ntok) chunk = Ntok;

    int MAXR = chunk / 2;
    if (MAXR > 4096) MAXR = 4096;

    const size_t regionBytes = (size_t)chunk * (2 * H2 + 2 * NEXP) * sizeof(float);

    float* buf0 = (float*)d_ws;
    float* buf1 = buf0 + (size_t)chunk * H2;
    float* lg   = buf1 + (size_t)chunk * H2;
    float* nl   = lg   + (size_t)chunk * NEXP;

    double* hA  = (double*)d_ws;                 // [MAXR, 2048]
    double* hB  = hA + (size_t)MAXR * H2;        // [MAXR, 2048]
    double* lgd = hB + (size_t)MAXR * H2;        // [MAXR, 64]
    double* nld = lgd + (size_t)MAXR * NEXP;     // [MAXR, 64]

    int* ctrl = (int*)((char*)d_ws + regionBytes);
    int* list = ctrl + 16;

    float* ridx = out + (size_t)Ntok * NEXP;

    const dim3 blk(256);
    init_kernel<<<1, 64, 0, stream>>>(ctrl);

    for (int c0 = 0; c0 < Ntok; c0 += chunk) {
        const float* xa = x + (size_t)c0 * IN_DIM;
        sgemm_relu_kernel<<<dim3(H2 / BN,  chunk / BM), blk, 0, stream>>>(xa,   w1, b1, buf0, H2,  IN_DIM);
        sgemm_relu_kernel<<<dim3(H2 / BN,  chunk / BM), blk, 0, stream>>>(buf0, w2, b2, buf1, H2,  H2);
        sgemm_relu_kernel<<<dim3(H2 / BN,  chunk / BM), blk, 0, stream>>>(buf1, wn, bn, buf0, H2,  H2);
        sgemm_relu_kernel<<<dim3(HID / BN, chunk / BM), blk, 0, stream>>>(buf0, w3, b3, buf1, HID, H2);
        small_gemm_kernel<<<dim3(chunk / SBM), blk, 0, stream>>>(buf1, w4, b4, lg, HID);
        small_gemm_kernel<<<dim3(chunk / SBM), blk, 0, stream>>>(xa,   wz, bz, nl, IN_DIM);
        router_kernel<<<dim3(chunk / 4), blk, 0, stream>>>(lg, nl, noise + (size_t)c0 * NEXP,
                                                           out + (size_t)c0 * NEXP,
                                                           ridx + (size_t)c0 * TOPK, chunk, c0,
                                                           ctrl, list, MAXR);
    }

    pad_kernel<<<1, 256, 0, stream>>>(ctrl, list, MAXR);

    const dim3 gy(H2 / DBN, MAXR / DBM);
    dgemm_f64<<<gy, blk, 0, stream>>>(nullptr, x, list, w1, b1, hA, H2, IN_DIM, 1, ctrl);
    dgemm_f64<<<gy, blk, 0, stream>>>(hA, nullptr, nullptr, w2, b2, hB, H2, H2, 1, ctrl);
    dgemm_f64<<<gy, blk, 0, stream>>>(hB, nullptr, nullptr, wn, bn, hA, H2, H2, 1, ctrl);
    dgemm_f64<<<dim3(HID / DBN, MAXR / DBM), blk, 0, stream>>>(hA, nullptr, nullptr, w3, b3, hB, HID, H2, 1, ctrl);
    dgemm_f64<<<dim3(1, MAXR / DBM), blk, 0, stream>>>(hB, nullptr, nullptr, w4, b4, lgd, NEXP, HID, 0, ctrl);
    dgemm_f64<<<dim3(1, MAXR / DBM), blk, 0, stream>>>(nullptr, x, list, wz, bz, nld, NEXP, IN_DIM, 0, ctrl);
    router_fix_kernel<<<dim3(MAXR / 4), blk, 0, stream>>>(lgd, nld, noise, out, ridx, ctrl, list);
}

// Round 4
// 13131.546 us; speedup vs baseline: 3.0541x; 3.0541x over previous
//
#include <hip/hip_runtime.h>
#include <math.h>

#define IN_DIM 1024
#define H2     2048
#define HID    1024
#define NEXP   64
#define TOPK   8
#define RISK_TH 1.5e-4f

// ---------------- big SGEMM: C = relu(A@B + bias), fp32 ----------------
// R3: __launch_bounds__(256,2) not (256,4) — at min-4-waves/EU the allocator
// capped at 64 VGPR and spilled the 8x8 accumulator to scratch (R3 counters:
// 5.8GB FETCH / 9.2GB WRITE per dispatch, VALUBusy 24%). 2 waves/EU -> 256
// VGPR budget, ~130 live regs fit with no spill.
#define BM 128
#define BN 128
#define BK 16
#define LDAS 132

__global__ __launch_bounds__(256, 2)
void sgemm_relu_kernel(const float* __restrict__ A, const float* __restrict__ B,
                       const float* __restrict__ bias, float* __restrict__ C,
                       int N, int K)
{
    __shared__ __align__(16) float As[BK][LDAS]; // As[k][m]
    __shared__ __align__(16) float Bs[BK][BN];   // Bs[k][n]

    const int tid = threadIdx.x;
    const int tx  = tid & 15;
    const int ty  = tid >> 4;
    const long bm = (long)blockIdx.y * BM;
    const long bn = (long)blockIdx.x * BN;

    const float* Ab = A + bm * K;
    const float* Bb = B + bn;

    float acc[8][8];
#pragma unroll
    for (int i = 0; i < 8; ++i)
#pragma unroll
        for (int j = 0; j < 8; ++j) acc[i][j] = 0.f;

    float4 aR[2], bR[2];
#pragma unroll
    for (int j = 0; j < 2; ++j) {
        int idx = tid + (j << 8);
        int ar = idx >> 2, ac = (idx & 3) << 2;
        aR[j] = *(const float4*)(Ab + (long)ar * K + ac);
        int br = idx >> 5, bc = (idx & 31) << 2;
        bR[j] = *(const float4*)(Bb + (long)br * N + bc);
    }

    int kt = 0;
    for (;;) {
#pragma unroll
        for (int j = 0; j < 2; ++j) {
            int idx = tid + (j << 8);
            int ar = idx >> 2, ac = (idx & 3) << 2;
            As[ac + 0][ar] = aR[j].x;
            As[ac + 1][ar] = aR[j].y;
            As[ac + 2][ar] = aR[j].z;
            As[ac + 3][ar] = aR[j].w;
            int br = idx >> 5, bc = (idx & 31) << 2;
            *(float4*)&Bs[br][bc] = bR[j];
        }
        __syncthreads();

        kt += BK;
        if (kt < K) {
#pragma unroll
            for (int j = 0; j < 2; ++j) {
                int idx = tid + (j << 8);
                int ar = idx >> 2, ac = (idx & 3) << 2;
                aR[j] = *(const float4*)(Ab + (long)ar * K + kt + ac);
                int br = idx >> 5, bc = (idx & 31) << 2;
                bR[j] = *(const float4*)(Bb + (long)(kt + br) * N + bc);
            }
        }

#pragma unroll
        for (int k = 0; k < BK; ++k) {
            float a[8], b[8];
            *(float4*)&a[0] = *(const float4*)&As[k][ty * 8];
            *(float4*)&a[4] = *(const float4*)&As[k][ty * 8 + 4];
            *(float4*)&b[0] = *(const float4*)&Bs[k][tx * 8];
            *(float4*)&b[4] = *(const float4*)&Bs[k][tx * 8 + 4];
#pragma unroll
            for (int i = 0; i < 8; ++i)
#pragma unroll
                for (int j = 0; j < 8; ++j)
                    acc[i][j] = fmaf(a[i], b[j], acc[i][j]);
        }
        __syncthreads();
        if (kt >= K) break;
    }

    float bv[8];
#pragma unroll
    for (int j = 0; j < 8; ++j) bv[j] = bias[bn + tx * 8 + j];
#pragma unroll
    for (int i = 0; i < 8; ++i) {
        long row = bm + ty * 8 + i;
        float o[8];
#pragma unroll
        for (int j = 0; j < 8; ++j) {
            float v = acc[i][j] + bv[j];
            o[j] = fmaxf(v, 0.f);
        }
        float* Cp = C + row * N + bn + tx * 8;
        *(float4*)(Cp)     = *(const float4*)&o[0];
        *(float4*)(Cp + 4) = *(const float4*)&o[4];
    }
}

// ---------------- small GEMM (N=64): C = A@B + bias, fp32 ----------------
#define SBM 64
#define SBK 32
#define SLDA 68

__global__ __launch_bounds__(256, 2)
void small_gemm_kernel(const float* __restrict__ A, const float* __restrict__ B,
                       const float* __restrict__ bias, float* __restrict__ C,
                       int K)
{
    __shared__ __align__(16) float Hs[SBK][SLDA];
    __shared__ __align__(16) float Ws[SBK][NEXP];
    const int tid = threadIdx.x;
    const int tx = tid & 15;
    const int ty = tid >> 4;
    const long bm = (long)blockIdx.x * SBM;
    const float* Ab = A + bm * K;

    float acc[4][4];
#pragma unroll
    for (int i = 0; i < 4; ++i)
#pragma unroll
        for (int j = 0; j < 4; ++j) acc[i][j] = 0.f;

    float4 aR[2], bR[2];
#pragma unroll
    for (int j = 0; j < 2; ++j) {
        int idx = tid + (j << 8);
        int ar = idx >> 3, ac = (idx & 7) << 2;
        aR[j] = *(const float4*)(Ab + (long)ar * K + ac);
        int br = idx >> 4, bc = (idx & 15) << 2;
        bR[j] = *(const float4*)(B + (long)br * NEXP + bc);
    }

    int kt = 0;
    for (;;) {
#pragma unroll
        for (int j = 0; j < 2; ++j) {
            int idx = tid + (j << 8);
            int ar = idx >> 3, ac = (idx & 7) << 2;
            Hs[ac + 0][ar] = aR[j].x;
            Hs[ac + 1][ar] = aR[j].y;
            Hs[ac + 2][ar] = aR[j].z;
            Hs[ac + 3][ar] = aR[j].w;
            int br = idx >> 4, bc = (idx & 15) << 2;
            *(float4*)&Ws[br][bc] = bR[j];
        }
        __syncthreads();

        kt += SBK;
        if (kt < K) {
#pragma unroll
            for (int j = 0; j < 2; ++j) {
                int idx = tid + (j << 8);
                int ar = idx >> 3, ac = (idx & 7) << 2;
                aR[j] = *(const float4*)(Ab + (long)ar * K + kt + ac);
                int br = idx >> 4, bc = (idx & 15) << 2;
                bR[j] = *(const float4*)(B + (long)(kt + br) * NEXP + bc);
            }
        }

#pragma unroll
        for (int k = 0; k < SBK; ++k) {
            float a[4], b[4];
            *(float4*)&a[0] = *(const float4*)&Hs[k][ty * 4];
            *(float4*)&b[0] = *(const float4*)&Ws[k][tx * 4];
#pragma unroll
            for (int i = 0; i < 4; ++i)
#pragma unroll
                for (int j = 0; j < 4; ++j)
                    acc[i][j] = fmaf(a[i], b[j], acc[i][j]);
        }
        __syncthreads();
        if (kt >= K) break;
    }

    float bv[4];
#pragma unroll
    for (int j = 0; j < 4; ++j) bv[j] = bias[tx * 4 + j];
#pragma unroll
    for (int i = 0; i < 4; ++i) {
        long row = bm + ty * 4 + i;
        float o[4];
#pragma unroll
        for (int j = 0; j < 4; ++j) o[j] = acc[i][j] + bv[j];
        *(float4*)(C + row * NEXP + tx * 4) = *(const float4*)&o[0];
    }
}

// ---------------- router (fp32) + risky-row detection ----------------
__global__ __launch_bounds__(256)
void router_kernel(const float* __restrict__ logits, const float* __restrict__ nlog,
                   const float* __restrict__ noise, float* __restrict__ rout,
                   float* __restrict__ idx_out, int rows, int rowBase,
                   int* __restrict__ ctrl, int* __restrict__ list, int maxr)
{
    const int wave = threadIdx.x >> 6;
    const int lane = threadIdx.x & 63;
    const long row = (long)blockIdx.x * 4 + wave;
    if (row >= rows) return;

    float lg = logits[row * NEXP + lane];
    float nl = nlog[row * NEXP + lane];
    float nz = noise[row * NEXP + lane];
    float sp = fmaxf(nl, 0.f) + log1pf(expf(-fabsf(nl)));
    float v  = lg + nz * sp;

    float orig = v;
    float work = v;
    bool  sel  = false;
    float myidx = 0.f;
    float m = 0.f, ssum = 0.f;
    float prev = 0.f, minGap = INFINITY;

#pragma unroll
    for (int r = 0; r < TOPK + 1; ++r) {   // 9 rounds: top-8 + gap to rank-9
        float bvv = work;
        int   bi  = lane;
#pragma unroll
        for (int off = 32; off > 0; off >>= 1) {
            float ov = __shfl_xor(bvv, off);
            int   oi = __shfl_xor(bi, off);
            if (ov > bvv || (ov == bvv && oi < bi)) { bvv = ov; bi = oi; }
        }
        if (r > 0) minGap = fminf(minGap, prev - bvv);
        prev = bvv;
        if (r < TOPK) {
            if (r == 0) m = bvv;
            ssum += expf(bvv - m);
            if (lane == bi) { work = -INFINITY; sel = true; }
            if (lane == r)  myidx = (float)bi;
        }
    }

    float p = sel ? expf(orig - m) / ssum : 0.f;
    rout[row * NEXP + lane] = p;
    if (lane < TOPK) idx_out[row * TOPK + lane] = myidx;

    if (lane == 0 && minGap < RISK_TH) {
        int slot = atomicAdd(ctrl, 1);
        if (slot < maxr) list[slot] = rowBase + (int)row;
    }
}

// ---------------- phase C: fp64 recompute of risky rows ----------------
__global__ void init_kernel(int* ctrl) { if (threadIdx.x == 0) ctrl[0] = 0; }

__global__ void pad_kernel(int* ctrl, int* list, int maxr)
{
    int cnt = ctrl[0]; if (cnt > maxr) cnt = maxr;
    int rounded = (cnt + 63) & ~63; if (rounded > maxr) rounded = maxr;
    if (threadIdx.x == 0) { ctrl[1] = rounded; ctrl[2] = cnt; }
    int fill = (cnt > 0) ? list[0] : 0;
    for (int i = cnt + threadIdx.x; i < rounded; i += blockDim.x) list[i] = fill;
}

#define DBM 64
#define DBN 64
#define DBK 16

__global__ __launch_bounds__(256)
void dgemm_f64(const double* __restrict__ A64, const float* __restrict__ A32,
               const int* __restrict__ rowList,
               const float* __restrict__ B, const float* __restrict__ bias,
               double* __restrict__ C, int N, int K, int doRelu,
               const int* __restrict__ ctrl)
{
    const int mBase = blockIdx.y * DBM;
    if (mBase >= ctrl[1]) return;

    __shared__ double As[DBK][DBM + 1];
    __shared__ double Bs[DBK][DBN];
    __shared__ int rowIdx[DBM];

    const int tid = threadIdx.x;
    const int tx = tid & 15;
    const int ty = tid >> 4;
    const int nBase = blockIdx.x * DBN;

    if (A32 && tid < DBM) rowIdx[tid] = rowList[mBase + tid];
    __syncthreads();

    double acc[4][4];
#pragma unroll
    for (int i = 0; i < 4; ++i)
#pragma unroll
        for (int j = 0; j < 4; ++j) acc[i][j] = 0.0;

    for (int kt = 0; kt < K; kt += DBK) {
#pragma unroll
        for (int j = 0; j < 4; ++j) {
            int idx = tid + (j << 8);
            int ar = idx >> 4, ak = idx & 15;
            double av;
            if (A32) av = (double)A32[(long)rowIdx[ar] * K + kt + ak];
            else     av = A64[(long)(mBase + ar) * K + kt + ak];
            As[ak][ar] = av;
            int br = idx >> 6, bc = idx & 63;
            Bs[br][bc] = (double)B[(long)(kt + br) * N + nBase + bc];
        }
        __syncthreads();

#pragma unroll
        for (int k = 0; k < DBK; ++k) {
            double a[4], b[4];
#pragma unroll
            for (int i = 0; i < 4; ++i) a[i] = As[k][ty * 4 + i];
#pragma unroll
            for (int j = 0; j < 4; ++j) b[j] = Bs[k][tx * 4 + j];
#pragma unroll
            for (int i = 0; i < 4; ++i)
#pragma unroll
                for (int j = 0; j < 4; ++j)
                    acc[i][j] = fma(a[i], b[j], acc[i][j]);
        }
        __syncthreads();
    }

#pragma unroll
    for (int i = 0; i < 4; ++i) {
        long row = mBase + ty * 4 + i;
#pragma unroll
        for (int j = 0; j < 4; ++j) {
            int n = nBase + tx * 4 + j;
            double v = acc[i][j] + (double)bias[n];
            if (doRelu) v = fmax(v, 0.0);
            C[row * N + n] = v;
        }
    }
}

__global__ __launch_bounds__(256)
void router_fix_kernel(const double* __restrict__ lgd, const double* __restrict__ nld,
                       const float* __restrict__ noise, float* __restrict__ rout,
                       float* __restrict__ idx_out,
                       const int* __restrict__ ctrl, const int* __restrict__ list)
{
    const int wave = threadIdx.x >> 6;
    const int lane = threadIdx.x & 63;
    const int i = blockIdx.x * 4 + wave;
    if (i >= ctrl[2]) return;
    const long row = list[i];

    double lg = lgd[(long)i * NEXP + lane];
    double nl = nld[(long)i * NEXP + lane];
    double nz = (double)noise[row * NEXP + lane];
    double sp = fmax(nl, 0.0) + log1p(exp(-fabs(nl)));
    double v  = lg + nz * sp;

    double orig = v, work = v;
    bool sel = false;
    float myidx = 0.f;
    double m = 0.0, ssum = 0.0;

#pragma unroll
    for (int r = 0; r < TOPK; ++r) {
        double bvv = work;
        int    bi  = lane;
#pragma unroll
        for (int off = 32; off > 0; off >>= 1) {
            double ov = __shfl_xor(bvv, off);
            int    oi = __shfl_xor(bi, off);
            if (ov > bvv || (ov == bvv && oi < bi)) { bvv = ov; bi = oi; }
        }
        if (r == 0) m = bvv;
        ssum += exp(bvv - m);
        if (lane == bi) { work = -INFINITY; sel = true; }
        if (lane == r)  myidx = (float)bi;
    }

    double p = sel ? exp(orig - m) / ssum : 0.0;
    rout[row * NEXP + lane] = (float)p;
    if (lane < TOPK) idx_out[row * TOPK + lane] = myidx;
}

// ---------------- launch ----------------
extern "C" void kernel_launch(void* const* d_in, const int* in_sizes, int n_in,
                              void* d_out, int out_size, void* d_ws, size_t ws_size,
                              hipStream_t stream)
{
    const float* x     = (const float*)d_in[0];
    const float* noise = (const float*)d_in[1];
    const float* w1 = (const float*)d_in[2];
    const float* b1 = (const float*)d_in[3];
    const float* w2 = (const float*)d_in[4];
    const float* b2 = (const float*)d_in[5];
    const float* wn = (const float*)d_in[6];
    const float* bn = (const float*)d_in[7];
    const float* w3 = (const float*)d_in[8];
    const float* b3 = (const float*)d_in[9];
    const float* w4 = (const float*)d_in[10];
    const float* b4 = (const float*)d_in[11];
    const float* wz = (const float*)d_in[12];
    const float* bz = (const float*)d_in[13];
    float* out = (float*)d_out;

    const int Ntok = in_sizes[0] / IN_DIM;   // 32768

    int chunk = 8192;
    while (chunk > 128) {
        size_t needb = (size_t)chunk * (2 * H2 + 2 * NEXP) * sizeof(float) + 32768;
        if (needb <= ws_size) break;
        chunk >>= 1;
    }
    if (chunk > Ntok) chunk = Ntok;

    int MAXR = chunk / 2;
    if (MAXR > 4096) MAXR = 4096;

    const size_t regionBytes = (size_t)chunk * (2 * H2 + 2 * NEXP) * sizeof(float);

    float* buf0 = (float*)d_ws;
    float* buf1 = buf0 + (size_t)chunk * H2;
    float* lg   = buf1 + (size_t)chunk * H2;
    float* nl   = lg   + (size_t)chunk * NEXP;

    double* hA  = (double*)d_ws;                 // [MAXR, 2048]
    double* hB  = hA + (size_t)MAXR * H2;        // [MAXR, 2048]
    double* lgd = hB + (size_t)MAXR * H2;        // [MAXR, 64]
    double* nld = lgd + (size_t)MAXR * NEXP;     // [MAXR, 64]

    int* ctrl = (int*)((char*)d_ws + regionBytes);
    int* list = ctrl + 16;

    float* ridx = out + (size_t)Ntok * NEXP;

    const dim3 blk(256);
    init_kernel<<<1, 64, 0, stream>>>(ctrl);

    for (int c0 = 0; c0 < Ntok; c0 += chunk) {
        const float* xa = x + (size_t)c0 * IN_DIM;
        sgemm_relu_kernel<<<dim3(H2 / BN,  chunk / BM), blk, 0, stream>>>(xa,   w1, b1, buf0, H2,  IN_DIM);
        sgemm_relu_kernel<<<dim3(H2 / BN,  chunk / BM), blk, 0, stream>>>(buf0, w2, b2, buf1, H2,  H2);
        sgemm_relu_kernel<<<dim3(H2 / BN,  chunk / BM), blk, 0, stream>>>(buf1, wn, bn, buf0, H2,  H2);
        sgemm_relu_kernel<<<dim3(HID / BN, chunk / BM), blk, 0, stream>>>(buf0, w3, b3, buf1, HID, H2);
        small_gemm_kernel<<<dim3(chunk / SBM), blk, 0, stream>>>(buf1, w4, b4, lg, HID);
        small_gemm_kernel<<<dim3(chunk / SBM), blk, 0, stream>>>(xa,   wz, bz, nl, IN_DIM);
        router_kernel<<<dim3(chunk / 4), blk, 0, stream>>>(lg, nl, noise + (size_t)c0 * NEXP,
                                                           out + (size_t)c0 * NEXP,
                                                           ridx + (size_t)c0 * TOPK, chunk, c0,
                                                           ctrl, list, MAXR);
    }

    pad_kernel<<<1, 256, 0, stream>>>(ctrl, list, MAXR);

    const dim3 gy(H2 / DBN, MAXR / DBM);
    dgemm_f64<<<gy, blk, 0, stream>>>(nullptr, x, list, w1, b1, hA, H2, IN_DIM, 1, ctrl);
    dgemm_f64<<<gy, blk, 0, stream>>>(hA, nullptr, nullptr, w2, b2, hB, H2, H2, 1, ctrl);
    dgemm_f64<<<gy, blk, 0, stream>>>(hB, nullptr, nullptr, wn, bn, hA, H2, H2, 1, ctrl);
    dgemm_f64<<<dim3(HID / DBN, MAXR / DBM), blk, 0, stream>>>(hA, nullptr, nullptr, w3, b3, hB, HID, H2, 1, ctrl);
    dgemm_f64<<<dim3(1, MAXR / DBM), blk, 0, stream>>>(hB, nullptr, nullptr, w4, b4, lgd, NEXP, HID, 0, ctrl);
    dgemm_f64<<<dim3(1, MAXR / DBM), blk, 0, stream>>>(nullptr, x, list, wz, bz, nld, NEXP, IN_DIM, 0, ctrl);
    router_fix_kernel<<<dim3(MAXR / 4), blk, 0, stream>>>(lgd, nld, noise, out, ridx, ctrl, list);
}

// Round 5
// 5491.529 us; speedup vs baseline: 7.3032x; 2.3912x over previous
//
#include <hip/hip_runtime.h>
#include <math.h>

#define IN_DIM 1024
#define H2     2048
#define HID    1024
#define NEXP   64
#define TOPK   8
#define RISK_TH 1.5e-4f

typedef short  v8s __attribute__((ext_vector_type(8)));   // 8 bf16 (MFMA A/B frag)
typedef float  v4f __attribute__((ext_vector_type(4)));   // 4 f32  (MFMA C/D frag)

// split fp32 -> bf16 hi + bf16 lo (truncation; combined 16-bit mantissa, rel err ~2^-16)
__device__ __forceinline__ void bf16_split(float f, ushort& h, ushort& l) {
    unsigned uh = __float_as_uint(f) & 0xffff0000u;
    h = (ushort)(uh >> 16);
    float r = f - __uint_as_float(uh);
    l = (ushort)(__float_as_uint(r) >> 16);
}

// ---------------- weight split+transpose: W[K,N] f32 -> WT_hi/lo[N,K] bf16 ----------------
__global__ __launch_bounds__(256)
void split_w_kernel(const float* __restrict__ W, ushort* __restrict__ hiT,
                    ushort* __restrict__ loT, int K, int N)
{
    __shared__ float T[64][65];
    const int k0 = blockIdx.y * 64, n0 = blockIdx.x * 64;
    const int t = threadIdx.x;
#pragma unroll
    for (int j = 0; j < 4; ++j) {
        int idx = t + j * 256;
        int row = idx >> 4;            // k-local 0..63
        int c4  = (idx & 15) * 4;      // n-local
        float4 f = *(const float4*)(W + (long)(k0 + row) * N + n0 + c4);
        T[row][c4 + 0] = f.x; T[row][c4 + 1] = f.y;
        T[row][c4 + 2] = f.z; T[row][c4 + 3] = f.w;
    }
    __syncthreads();
#pragma unroll
    for (int j = 0; j < 4; ++j) {
        int idx = t + j * 256;
        int nn = idx >> 4;             // n-local 0..63
        int kq = (idx & 15) * 4;       // k-local
        ushort4 h4, l4;
        bf16_split(T[kq + 0][nn], h4.x, l4.x);
        bf16_split(T[kq + 1][nn], h4.y, l4.y);
        bf16_split(T[kq + 2][nn], h4.z, l4.z);
        bf16_split(T[kq + 3][nn], h4.w, l4.w);
        long o = (long)(n0 + nn) * K + k0 + kq;
        *(ushort4*)(hiT + o) = h4;
        *(ushort4*)(loT + o) = l4;
    }
}

// ---------------- big GEMM: C = relu(A@B + bias) via bf16x3 MFMA ----------------
// A fp32 [M,K] (split to hi/lo bf16 while staging); B pre-split bf16 planes [N,K].
// 128x128x32 tile, 4 waves (2x2), wave = 4x4 cells of mfma_f32_16x16x32_bf16.
// Verified layouts (m89/m91): A[m=lane&15][k=quad*8+j], B[n=lane&15][k=quad*8+j],
// D col=lane&15, row=quad*4+reg.
#define GBM 128
#define GBN 128
#define GBK 32
#define LDK 40   // LDS k-stride (bf16): 80B/row -> frag reads at bank minimum

__global__ __launch_bounds__(256, 2)
void gemm_bf16x3_kernel(const float* __restrict__ A,
                        const ushort* __restrict__ BThi, const ushort* __restrict__ BTlo,
                        const float* __restrict__ bias, float* __restrict__ C,
                        int N, int K)
{
    __shared__ __align__(16) ushort Ahi[GBM * LDK];
    __shared__ __align__(16) ushort Alo[GBM * LDK];
    __shared__ __align__(16) ushort Bhi[GBN * LDK];
    __shared__ __align__(16) ushort Blo[GBN * LDK];   // 4 x 10240B = 40KB

    const int tid  = threadIdx.x;
    const int lane = tid & 63;
    const int wave = tid >> 6;
    const int waveM = (wave >> 1) * 64;
    const int waveN = (wave & 1) * 64;
    const int quad = lane >> 4;
    const int l15  = lane & 15;
    const long bm = (long)blockIdx.y * GBM;
    const long bn = (long)blockIdx.x * GBN;

    v4f acc[4][4];
#pragma unroll
    for (int mi = 0; mi < 4; ++mi)
#pragma unroll
        for (int ni = 0; ni < 4; ++ni)
            acc[mi][ni] = (v4f){0.f, 0.f, 0.f, 0.f};

    for (int kt = 0; kt < K; kt += GBK) {
        // stage A: 128 rows x 32 k fp32 -> hi/lo bf16. 2 threads/row, 16 k each.
        {
            const int r  = tid >> 1;
            const int kq = (tid & 1) * 16;
            const float* src = A + (bm + r) * K + kt + kq;
            ushort* dh = Ahi + r * LDK + kq;
            ushort* dl = Alo + r * LDK + kq;
#pragma unroll
            for (int i = 0; i < 4; ++i) {
                float4 f = *(const float4*)(src + i * 4);
                ushort4 h4, l4;
                bf16_split(f.x, h4.x, l4.x);
                bf16_split(f.y, h4.y, l4.y);
                bf16_split(f.z, h4.z, l4.z);
                bf16_split(f.w, h4.w, l4.w);
                *(ushort4*)(dh + i * 4) = h4;
                *(ushort4*)(dl + i * 4) = l4;
            }
        }
        // stage B: 128 n-rows x 32 k bf16 per plane. waves 0-1: hi, waves 2-3: lo.
        {
            const int r  = tid & 127;
            const int pl = tid >> 7;                  // wave-uniform
            const ushort* src = (pl ? BTlo : BThi) + (bn + r) * K + kt;
            ushort* dst = (pl ? Blo : Bhi) + r * LDK;
#pragma unroll
            for (int i = 0; i < 4; ++i)
                *(uint4*)(dst + i * 8) = *(const uint4*)(src + i * 8);
        }
        __syncthreads();

        v8s ah[4], al[4];
#pragma unroll
        for (int mi = 0; mi < 4; ++mi) {
            int r = waveM + mi * 16 + l15;
            ah[mi] = *(v8s*)(Ahi + r * LDK + quad * 8);
            al[mi] = *(v8s*)(Alo + r * LDK + quad * 8);
        }
#pragma unroll
        for (int ni = 0; ni < 4; ++ni) {
            int r = waveN + ni * 16 + l15;
            v8s bh = *(v8s*)(Bhi + r * LDK + quad * 8);
            v8s bl = *(v8s*)(Blo + r * LDK + quad * 8);
#pragma unroll
            for (int mi = 0; mi < 4; ++mi) {
                acc[mi][ni] = __builtin_amdgcn_mfma_f32_16x16x32_bf16(al[mi], bh, acc[mi][ni], 0, 0, 0);
                acc[mi][ni] = __builtin_amdgcn_mfma_f32_16x16x32_bf16(ah[mi], bl, acc[mi][ni], 0, 0, 0);
                acc[mi][ni] = __builtin_amdgcn_mfma_f32_16x16x32_bf16(ah[mi], bh, acc[mi][ni], 0, 0, 0);
            }
        }
        __syncthreads();
    }

    // epilogue: bias + relu
#pragma unroll
    for (int ni = 0; ni < 4; ++ni) {
        int col = (int)bn + waveN + ni * 16 + l15;
        float bv = bias[col];
#pragma unroll
        for (int mi = 0; mi < 4; ++mi) {
            long row0 = bm + waveM + mi * 16 + quad * 4;
#pragma unroll
            for (int r = 0; r < 4; ++r) {
                float v = acc[mi][ni][r] + bv;
                C[(row0 + r) * N + col] = fmaxf(v, 0.f);
            }
        }
    }
}

// ---------------- small GEMM (N=64): C = A@B + bias, fp32 ----------------
#define SBM 64
#define SBK 32
#define SLDA 68

__global__ __launch_bounds__(256, 2)
void small_gemm_kernel(const float* __restrict__ A, const float* __restrict__ B,
                       const float* __restrict__ bias, float* __restrict__ C,
                       int K)
{
    __shared__ __align__(16) float Hs[SBK][SLDA];
    __shared__ __align__(16) float Ws[SBK][NEXP];
    const int tid = threadIdx.x;
    const int tx = tid & 15;
    const int ty = tid >> 4;
    const long bm = (long)blockIdx.x * SBM;
    const float* Ab = A + bm * K;

    float acc[4][4];
#pragma unroll
    for (int i = 0; i < 4; ++i)
#pragma unroll
        for (int j = 0; j < 4; ++j) acc[i][j] = 0.f;

    float4 aR[2], bR[2];
#pragma unroll
    for (int j = 0; j < 2; ++j) {
        int idx = tid + (j << 8);
        int ar = idx >> 3, ac = (idx & 7) << 2;
        aR[j] = *(const float4*)(Ab + (long)ar * K + ac);
        int br = idx >> 4, bc = (idx & 15) << 2;
        bR[j] = *(const float4*)(B + (long)br * NEXP + bc);
    }

    int kt = 0;
    for (;;) {
#pragma unroll
        for (int j = 0; j < 2; ++j) {
            int idx = tid + (j << 8);
            int ar = idx >> 3, ac = (idx & 7) << 2;
            Hs[ac + 0][ar] = aR[j].x;
            Hs[ac + 1][ar] = aR[j].y;
            Hs[ac + 2][ar] = aR[j].z;
            Hs[ac + 3][ar] = aR[j].w;
            int br = idx >> 4, bc = (idx & 15) << 2;
            *(float4*)&Ws[br][bc] = bR[j];
        }
        __syncthreads();

        kt += SBK;
        if (kt < K) {
#pragma unroll
            for (int j = 0; j < 2; ++j) {
                int idx = tid + (j << 8);
                int ar = idx >> 3, ac = (idx & 7) << 2;
                aR[j] = *(const float4*)(Ab + (long)ar * K + kt + ac);
                int br = idx >> 4, bc = (idx & 15) << 2;
                bR[j] = *(const float4*)(B + (long)(kt + br) * NEXP + bc);
            }
        }

#pragma unroll
        for (int k = 0; k < SBK; ++k) {
            float a[4], b[4];
            *(float4*)&a[0] = *(const float4*)&Hs[k][ty * 4];
            *(float4*)&b[0] = *(const float4*)&Ws[k][tx * 4];
#pragma unroll
            for (int i = 0; i < 4; ++i)
#pragma unroll
                for (int j = 0; j < 4; ++j)
                    acc[i][j] = fmaf(a[i], b[j], acc[i][j]);
        }
        __syncthreads();
        if (kt >= K) break;
    }

    float bv[4];
#pragma unroll
    for (int j = 0; j < 4; ++j) bv[j] = bias[tx * 4 + j];
#pragma unroll
    for (int i = 0; i < 4; ++i) {
        long row = bm + ty * 4 + i;
        float o[4];
#pragma unroll
        for (int j = 0; j < 4; ++j) o[j] = acc[i][j] + bv[j];
        *(float4*)(C + row * NEXP + tx * 4) = *(const float4*)&o[0];
    }
}

// ---------------- router (fp32) + risky-row detection ----------------
__global__ __launch_bounds__(256)
void router_kernel(const float* __restrict__ logits, const float* __restrict__ nlog,
                   const float* __restrict__ noise, float* __restrict__ rout,
                   float* __restrict__ idx_out, int rows, int rowBase,
                   int* __restrict__ ctrl, int* __restrict__ list, int maxr)
{
    const int wave = threadIdx.x >> 6;
    const int lane = threadIdx.x & 63;
    const long row = (long)blockIdx.x * 4 + wave;
    if (row >= rows) return;

    float lg = logits[row * NEXP + lane];
    float nl = nlog[row * NEXP + lane];
    float nz = noise[row * NEXP + lane];
    float sp = fmaxf(nl, 0.f) + log1pf(expf(-fabsf(nl)));
    float v  = lg + nz * sp;

    float orig = v;
    float work = v;
    bool  sel  = false;
    float myidx = 0.f;
    float m = 0.f, ssum = 0.f;
    float prev = 0.f, minGap = INFINITY;

#pragma unroll
    for (int r = 0; r < TOPK + 1; ++r) {
        float bvv = work;
        int   bi  = lane;
#pragma unroll
        for (int off = 32; off > 0; off >>= 1) {
            float ov = __shfl_xor(bvv, off);
            int   oi = __shfl_xor(bi, off);
            if (ov > bvv || (ov == bvv && oi < bi)) { bvv = ov; bi = oi; }
        }
        if (r > 0) minGap = fminf(minGap, prev - bvv);
        prev = bvv;
        if (r < TOPK) {
            if (r == 0) m = bvv;
            ssum += expf(bvv - m);
            if (lane == bi) { work = -INFINITY; sel = true; }
            if (lane == r)  myidx = (float)bi;
        }
    }

    float p = sel ? expf(orig - m) / ssum : 0.f;
    rout[row * NEXP + lane] = p;
    if (lane < TOPK) idx_out[row * TOPK + lane] = myidx;

    if (lane == 0 && minGap < RISK_TH) {
        int slot = atomicAdd(ctrl, 1);
        if (slot < maxr) list[slot] = rowBase + (int)row;
    }
}

// ---------------- phase C: fp64 recompute of risky rows ----------------
__global__ void init_kernel(int* ctrl) { if (threadIdx.x == 0) ctrl[0] = 0; }

__global__ void pad_kernel(int* ctrl, int* list, int maxr)
{
    int cnt = ctrl[0]; if (cnt > maxr) cnt = maxr;
    int rounded = (cnt + 63) & ~63; if (rounded > maxr) rounded = maxr;
    if (threadIdx.x == 0) { ctrl[1] = rounded; ctrl[2] = cnt; }
    int fill = (cnt > 0) ? list[0] : 0;
    for (int i = cnt + threadIdx.x; i < rounded; i += blockDim.x) list[i] = fill;
}

#define DBM 64
#define DBN 64
#define DBK 16

__global__ __launch_bounds__(256)
void dgemm_f64(const double* __restrict__ A64, const float* __restrict__ A32,
               const int* __restrict__ rowList,
               const float* __restrict__ B, const float* __restrict__ bias,
               double* __restrict__ C, int N, int K, int doRelu,
               const int* __restrict__ ctrl)
{
    const int mBase = blockIdx.y * DBM;
    if (mBase >= ctrl[1]) return;

    __shared__ double As[DBK][DBM + 1];
    __shared__ double Bs[DBK][DBN];
    __shared__ int rowIdx[DBM];

    const int tid = threadIdx.x;
    const int tx = tid & 15;
    const int ty = tid >> 4;
    const int nBase = blockIdx.x * DBN;

    if (A32 && tid < DBM) rowIdx[tid] = rowList[mBase + tid];
    __syncthreads();

    double acc[4][4];
#pragma unroll
    for (int i = 0; i < 4; ++i)
#pragma unroll
        for (int j = 0; j < 4; ++j) acc[i][j] = 0.0;

    for (int kt = 0; kt < K; kt += DBK) {
#pragma unroll
        for (int j = 0; j < 4; ++j) {
            int idx = tid + (j << 8);
            int ar = idx >> 4, ak = idx & 15;
            double av;
            if (A32) av = (double)A32[(long)rowIdx[ar] * K + kt + ak];
            else     av = A64[(long)(mBase + ar) * K + kt + ak];
            As[ak][ar] = av;
            int br = idx >> 6, bc = idx & 63;
            Bs[br][bc] = (double)B[(long)(kt + br) * N + nBase + bc];
        }
        __syncthreads();

#pragma unroll
        for (int k = 0; k < DBK; ++k) {
            double a[4], b[4];
#pragma unroll
            for (int i = 0; i < 4; ++i) a[i] = As[k][ty * 4 + i];
#pragma unroll
            for (int j = 0; j < 4; ++j) b[j] = Bs[k][tx * 4 + j];
#pragma unroll
            for (int i = 0; i < 4; ++i)
#pragma unroll
                for (int j = 0; j < 4; ++j)
                    acc[i][j] = fma(a[i], b[j], acc[i][j]);
        }
        __syncthreads();
    }

#pragma unroll
    for (int i = 0; i < 4; ++i) {
        long row = mBase + ty * 4 + i;
#pragma unroll
        for (int j = 0; j < 4; ++j) {
            int n = nBase + tx * 4 + j;
            double v = acc[i][j] + (double)bias[n];
            if (doRelu) v = fmax(v, 0.0);
            C[row * N + n] = v;
        }
    }
}

__global__ __launch_bounds__(256)
void router_fix_kernel(const double* __restrict__ lgd, const double* __restrict__ nld,
                       const float* __restrict__ noise, float* __restrict__ rout,
                       float* __restrict__ idx_out,
                       const int* __restrict__ ctrl, const int* __restrict__ list)
{
    const int wave = threadIdx.x >> 6;
    const int lane = threadIdx.x & 63;
    const int i = blockIdx.x * 4 + wave;
    if (i >= ctrl[2]) return;
    const long row = list[i];

    double lg = lgd[(long)i * NEXP + lane];
    double nl = nld[(long)i * NEXP + lane];
    double nz = (double)noise[row * NEXP + lane];
    double sp = fmax(nl, 0.0) + log1p(exp(-fabs(nl)));
    double v  = lg + nz * sp;

    double orig = v, work = v;
    bool sel = false;
    float myidx = 0.f;
    double m = 0.0, ssum = 0.0;

#pragma unroll
    for (int r = 0; r < TOPK; ++r) {
        double bvv = work;
        int    bi  = lane;
#pragma unroll
        for (int off = 32; off > 0; off >>= 1) {
            double ov = __shfl_xor(bvv, off);
            int    oi = __shfl_xor(bi, off);
            if (ov > bvv || (ov == bvv && oi < bi)) { bvv = ov; bi = oi; }
        }
        if (r == 0) m = bvv;
        ssum += exp(bvv - m);
        if (lane == bi) { work = -INFINITY; sel = true; }
        if (lane == r)  myidx = (float)bi;
    }

    double p = sel ? exp(orig - m) / ssum : 0.0;
    rout[row * NEXP + lane] = (float)p;
    if (lane < TOPK) idx_out[row * TOPK + lane] = myidx;
}

// ---------------- launch ----------------
extern "C" void kernel_launch(void* const* d_in, const int* in_sizes, int n_in,
                              void* d_out, int out_size, void* d_ws, size_t ws_size,
                              hipStream_t stream)
{
    const float* x     = (const float*)d_in[0];
    const float* noise = (const float*)d_in[1];
    const float* w1 = (const float*)d_in[2];
    const float* b1 = (const float*)d_in[3];
    const float* w2 = (const float*)d_in[4];
    const float* b2 = (const float*)d_in[5];
    const float* wn = (const float*)d_in[6];
    const float* bn = (const float*)d_in[7];
    const float* w3 = (const float*)d_in[8];
    const float* b3 = (const float*)d_in[9];
    const float* w4 = (const float*)d_in[10];
    const float* b4 = (const float*)d_in[11];
    const float* wz = (const float*)d_in[12];
    const float* bz = (const float*)d_in[13];
    float* out = (float*)d_out;

    const int Ntok = in_sizes[0] / IN_DIM;   // 32768

    // --- ws layout: [weight bf16 planes][chunk fp32 region / fp64 overlay][ctrl+list] ---
    const size_t e1 = (size_t)IN_DIM * H2;   // w1
    const size_t e2 = (size_t)H2 * H2;       // w2
    const size_t en = (size_t)H2 * H2;       // wn
    const size_t e3 = (size_t)H2 * HID;      // w3
    size_t weightBytes = 2 * (e1 + e2 + en + e3) * sizeof(ushort);
    weightBytes = (weightBytes + 255) & ~(size_t)255;

    int chunk = 8192;
    while (chunk > 128) {
        size_t needb = weightBytes + (size_t)chunk * (2 * H2 + 2 * NEXP) * sizeof(float) + 65536;
        if (needb <= ws_size) break;
        chunk >>= 1;
    }
    if (chunk > Ntok) chunk = Ntok;

    int MAXR = chunk / 2;
    if (MAXR > 4096) MAXR = 4096;

    ushort* w1Thi = (ushort*)d_ws;
    ushort* w1Tlo = w1Thi + e1;
    ushort* w2Thi = w1Tlo + e1;
    ushort* w2Tlo = w2Thi + e2;
    ushort* wnThi = w2Tlo + e2;
    ushort* wnTlo = wnThi + en;
    ushort* w3Thi = wnTlo + en;
    ushort* w3Tlo = w3Thi + e3;

    char* region = (char*)d_ws + weightBytes;
    const size_t regionBytes = (size_t)chunk * (2 * H2 + 2 * NEXP) * sizeof(float);

    float* buf0 = (float*)region;
    float* buf1 = buf0 + (size_t)chunk * H2;
    float* lg   = buf1 + (size_t)chunk * H2;
    float* nl   = lg   + (size_t)chunk * NEXP;

    double* hA  = (double*)region;               // [MAXR, 2048]
    double* hB  = hA + (size_t)MAXR * H2;
    double* lgd = hB + (size_t)MAXR * H2;        // [MAXR, 64]
    double* nld = lgd + (size_t)MAXR * NEXP;

    int* ctrl = (int*)(region + regionBytes);
    int* list = ctrl + 16;

    float* ridx = out + (size_t)Ntok * NEXP;

    const dim3 blk(256);
    init_kernel<<<1, 64, 0, stream>>>(ctrl);

    // weight split (every launch: ws is re-poisoned by the harness)
    split_w_kernel<<<dim3(H2 / 64,  IN_DIM / 64), blk, 0, stream>>>(w1, w1Thi, w1Tlo, IN_DIM, H2);
    split_w_kernel<<<dim3(H2 / 64,  H2 / 64),     blk, 0, stream>>>(w2, w2Thi, w2Tlo, H2, H2);
    split_w_kernel<<<dim3(H2 / 64,  H2 / 64),     blk, 0, stream>>>(wn, wnThi, wnTlo, H2, H2);
    split_w_kernel<<<dim3(HID / 64, H2 / 64),     blk, 0, stream>>>(w3, w3Thi, w3Tlo, H2, HID);

    for (int c0 = 0; c0 < Ntok; c0 += chunk) {
        const float* xa = x + (size_t)c0 * IN_DIM;
        gemm_bf16x3_kernel<<<dim3(H2 / GBN,  chunk / GBM), blk, 0, stream>>>(xa,   w1Thi, w1Tlo, b1, buf0, H2,  IN_DIM);
        gemm_bf16x3_kernel<<<dim3(H2 / GBN,  chunk / GBM), blk, 0, stream>>>(buf0, w2Thi, w2Tlo, b2, buf1, H2,  H2);
        gemm_bf16x3_kernel<<<dim3(H2 / GBN,  chunk / GBM), blk, 0, stream>>>(buf1, wnThi, wnTlo, bn, buf0, H2,  H2);
        gemm_bf16x3_kernel<<<dim3(HID / GBN, chunk / GBM), blk, 0, stream>>>(buf0, w3Thi, w3Tlo, b3, buf1, HID, H2);
        small_gemm_kernel<<<dim3(chunk / SBM), blk, 0, stream>>>(buf1, w4, b4, lg, HID);
        small_gemm_kernel<<<dim3(chunk / SBM), blk, 0, stream>>>(xa,   wz, bz, nl, IN_DIM);
        router_kernel<<<dim3(chunk / 4), blk, 0, stream>>>(lg, nl, noise + (size_t)c0 * NEXP,
                                                           out + (size_t)c0 * NEXP,
                                                           ridx + (size_t)c0 * TOPK, chunk, c0,
                                                           ctrl, list, MAXR);
    }

    pad_kernel<<<1, 256, 0, stream>>>(ctrl, list, MAXR);

    const dim3 gy(H2 / DBN, MAXR / DBM);
    dgemm_f64<<<gy, blk, 0, stream>>>(nullptr, x, list, w1, b1, hA, H2, IN_DIM, 1, ctrl);
    dgemm_f64<<<gy, blk, 0, stream>>>(hA, nullptr, nullptr, w2, b2, hB, H2, H2, 1, ctrl);
    dgemm_f64<<<gy, blk, 0, stream>>>(hB, nullptr, nullptr, wn, bn, hA, H2, H2, 1, ctrl);
    dgemm_f64<<<dim3(HID / DBN, MAXR / DBM), blk, 0, stream>>>(hA, nullptr, nullptr, w3, b3, hB, HID, H2, 1, ctrl);
    dgemm_f64<<<dim3(1, MAXR / DBM), blk, 0, stream>>>(hB, nullptr, nullptr, w4, b4, lgd, NEXP, HID, 0, ctrl);
    dgemm_f64<<<dim3(1, MAXR / DBM), blk, 0, stream>>>(nullptr, x, list, wz, bz, nld, NEXP, IN_DIM, 0, ctrl);
    router_fix_kernel<<<dim3(MAXR / 4), blk, 0, stream>>>(lgd, nld, noise, out, ridx, ctrl, list);
}